// Round 6
// baseline (1335.071 us; speedup 1.0000x reference)
//
#include <hip/hip_runtime.h>
#include <math.h>

#define SEQ    2048
#define BATCH  8
#define EMB    1024
#define HEADS  8
#define PROJ   64
#define CHAINS 64            // BATCH*HEADS
#define GATES  192           // 3*PROJ

typedef float f4  __attribute__((ext_vector_type(4)));
typedef short s8v __attribute__((ext_vector_type(8)));
typedef _Float16 h2v __attribute__((ext_vector_type(2)));

#define AS1(p) ((const __attribute__((address_space(1))) void*)(p))
#define AS3(p) ((__attribute__((address_space(3))) void*)(p))

static __device__ __forceinline__ float bf2f(unsigned short u) {
    union { unsigned int i; float f; } c; c.i = ((unsigned int)u) << 16; return c.f;
}
static __device__ __forceinline__ unsigned short f2bf(float f) {
    union { float f; unsigned int i; } c; c.f = f;
    unsigned int u = c.i;
    u += 0x7fffu + ((u >> 16) & 1u);   // round-to-nearest-even
    return (unsigned short)(u >> 16);
}
// dot2: c += a.x*b.x + a.y*b.y   (f16 inputs, f32 accum)
static __device__ __forceinline__ float fdot2u(unsigned int a, unsigned int b, float c) {
    union { unsigned int u; h2v h; } ua, ub; ua.u = a; ub.u = b;
    return __builtin_amdgcn_fdot2(ua.h, ub.h, c, false);
}

// ---------------------------------------------------------------------------
// f32 [R][C] -> bf16 out [C][R]   (32x32 LDS tile, both sides coalesced)
// ---------------------------------------------------------------------------
__global__ __launch_bounds__(256)
void transpose_to_bf16(const float* __restrict__ in, unsigned short* __restrict__ out,
                       int R, int C) {
    __shared__ float tile[32][33];
    const int tx = threadIdx.x & 31, ty = threadIdx.x >> 5;
    const int c0 = blockIdx.x * 32, r0 = blockIdx.y * 32;
#pragma unroll
    for (int i = 0; i < 4; ++i)
        tile[ty + i * 8][tx] = in[(size_t)(r0 + ty + i * 8) * C + c0 + tx];
    __syncthreads();
#pragma unroll
    for (int i = 0; i < 4; ++i)
        out[(size_t)(c0 + ty + i * 8) * R + r0 + tx] = f2bf(tile[tx][ty + i * 8]);
}

__global__ void convert_bf16(const float* __restrict__ in, unsigned short* __restrict__ out, int n) {
    const int i = blockIdx.x * blockDim.x + threadIdx.x;
    if (i < n) out[i] = f2bf(in[i]);
}

__global__ void convert_f16(const float* __restrict__ in, unsigned short* __restrict__ out, int n) {
    const int i = blockIdx.x * blockDim.x + threadIdx.x;
    if (i < n) {
        union { _Float16 h; unsigned short u; } c;
        c.h = (_Float16)in[i];
        out[i] = c.u;
    }
}

// ---------------------------------------------------------------------------
// bf16 MFMA GEMM:  C[M][N] = A[M][K] * BT[N][K]^T  (+ bias[N])
// PERM: output row m -> (m&63)*SEQ + (m>>6)   (ig relayout [s][c] -> [c][s])
// ---------------------------------------------------------------------------
template <int BM, int BN, int BK, bool A_F32, typename OutT, bool BIAS, bool PERM>
__global__ __launch_bounds__((BM / 64) * (BN / 64) * 64)
void gemm_mfma(const void* __restrict__ Ap, const unsigned short* __restrict__ BT,
               OutT* __restrict__ C, const float* __restrict__ bias,
               int M, int N, int K) {
    constexpr int NWN = BN / 64;
    constexpr int NW  = (BM / 64) * NWN;
    constexpr int NT  = NW * 64;
    constexpr int KP  = BK + 8;            // padded row (bf16 elems)
    __shared__ unsigned short Al[BM * KP];
    __shared__ unsigned short Bl[BN * KP];

    const int t    = threadIdx.x, lane = t & 63, wid = t >> 6;
    const int wm   = (wid / NWN) * 64, wn = (wid % NWN) * 64;
    const int bm   = blockIdx.x * BM, bn = blockIdx.y * BN;
    const int fr   = lane & 15;
    const int fq   = lane >> 4;

    f4 acc[4][4];
#pragma unroll
    for (int m = 0; m < 4; ++m)
#pragma unroll
        for (int n = 0; n < 4; ++n) acc[m][n] = f4{0.f, 0.f, 0.f, 0.f};

    const int nkt = K / BK;
    for (int kt = 0; kt < nkt; ++kt) {
        const int k0 = kt * BK;
        __syncthreads();
        constexpr int CHA = (BM * BK / 8) / NT;
#pragma unroll
        for (int i = 0; i < CHA; ++i) {
            const int ci = t + i * NT;
            const int r = ci / (BK / 8), cc = (ci % (BK / 8)) * 8;
            if constexpr (A_F32) {
                const float* A = (const float*)Ap;
                const float4 u0 = *(const float4*)&A[(size_t)(bm + r) * K + k0 + cc];
                const float4 u1 = *(const float4*)&A[(size_t)(bm + r) * K + k0 + cc + 4];
                s8v w;
                w[0] = (short)f2bf(u0.x); w[1] = (short)f2bf(u0.y);
                w[2] = (short)f2bf(u0.z); w[3] = (short)f2bf(u0.w);
                w[4] = (short)f2bf(u1.x); w[5] = (short)f2bf(u1.y);
                w[6] = (short)f2bf(u1.z); w[7] = (short)f2bf(u1.w);
                *(s8v*)&Al[r * KP + cc] = w;
            } else {
                const unsigned short* A = (const unsigned short*)Ap;
                *(s8v*)&Al[r * KP + cc] = *(const s8v*)&A[(size_t)(bm + r) * K + k0 + cc];
            }
        }
        constexpr int CHB = (BN * BK / 8) / NT;
#pragma unroll
        for (int i = 0; i < CHB; ++i) {
            const int ci = t + i * NT;
            const int r = ci / (BK / 8), cc = (ci % (BK / 8)) * 8;
            *(s8v*)&Bl[r * KP + cc] = *(const s8v*)&BT[(size_t)(bn + r) * K + k0 + cc];
        }
        __syncthreads();
#pragma unroll
        for (int ks = 0; ks < BK / 32; ++ks) {
            s8v av[4], bv[4];
#pragma unroll
            for (int m = 0; m < 4; ++m)
                av[m] = *(const s8v*)&Al[(wm + m * 16 + fr) * KP + ks * 32 + fq * 8];
#pragma unroll
            for (int n = 0; n < 4; ++n)
                bv[n] = *(const s8v*)&Bl[(wn + n * 16 + fr) * KP + ks * 32 + fq * 8];
#pragma unroll
            for (int m = 0; m < 4; ++m)
#pragma unroll
                for (int n = 0; n < 4; ++n)
                    acc[m][n] = __builtin_amdgcn_mfma_f32_16x16x32_bf16(
                        av[m], bv[n], acc[m][n], 0, 0, 0);
        }
    }

#pragma unroll
    for (int n = 0; n < 4; ++n) {
        const int col = bn + wn + n * 16 + fr;
        const float bv = BIAS ? bias[col] : 0.f;
#pragma unroll
        for (int m = 0; m < 4; ++m) {
            const int row0 = bm + wm + m * 16 + fq * 4;
#pragma unroll
            for (int j = 0; j < 4; ++j) {
                const float val = acc[m][n][j] + bv;
                const int row = row0 + j;
                const size_t orow = PERM ? ((size_t)(row & 63) * SEQ + (row >> 6))
                                         : (size_t)row;
                if constexpr (sizeof(OutT) == 4)
                    C[orow * N + col] = val;
                else
                    C[orow * N + col] = f2bf(val);
            }
        }
    }
}

// ---------------------------------------------------------------------------
// GRU scan v6: TWO chains per wave (shared w_hh registers), 32 blocks.
// Chain A's LDS h round-trip and transcendental latency hide under chain B's
// 96-dot issue block and vice versa -> issue-bound (~560 cy/step-pair)
// instead of dependency-bound (~780 cy/step).
// Block-boundary wait uses vmcnt(32): the 12 ig prefetch loads are the oldest
// VMEM ops; don't drain the ~32 in-flight ys stores.
// ---------------------------------------------------------------------------
__global__ __launch_bounds__(64, 1)
void gru_scan6(const unsigned short* __restrict__ w_hh16, const float* __restrict__ b_n,
               const unsigned short* __restrict__ ig, unsigned short* __restrict__ ys) {
    const int blk = blockIdx.x;                // 0..31
    const int cA = 2 * blk, cB = 2 * blk + 1;
    const int p = threadIdx.x;                 // 0..63

    __shared__ unsigned short hA16[PROJ];      // h_A as f16 (128 B)
    __shared__ unsigned short hB16[PROJ];
    __shared__ uint4 iglA[2][384];             // 2 x 6144 B (16 steps x 384 B)
    __shared__ uint4 iglB[2][384];

    // shared cell weights: rows {p, 64+p, 128+p} as f16 pairs (96 VGPRs)
    unsigned int wru[32], wzu[32], wnu[32];
#pragma unroll
    for (int q = 0; q < 8; ++q) {
        const uint4 a = *(const uint4*)&w_hh16[(size_t)(0 * PROJ + p) * PROJ + q * 8];
        wru[4*q+0] = a.x; wru[4*q+1] = a.y; wru[4*q+2] = a.z; wru[4*q+3] = a.w;
        const uint4 b = *(const uint4*)&w_hh16[(size_t)(1 * PROJ + p) * PROJ + q * 8];
        wzu[4*q+0] = b.x; wzu[4*q+1] = b.y; wzu[4*q+2] = b.z; wzu[4*q+3] = b.w;
        const uint4 e = *(const uint4*)&w_hh16[(size_t)(2 * PROJ + p) * PROJ + q * 8];
        wnu[4*q+0] = e.x; wnu[4*q+1] = e.y; wnu[4*q+2] = e.z; wnu[4*q+3] = e.w;
    }
    const float bn = b_n[p];

    hA16[p] = 0; hB16[p] = 0;
    float hregA = 0.f, hregB = 0.f;
    unsigned int hwA[32], hwB[32];
#pragma unroll
    for (int i = 0; i < 32; ++i) { hwA[i] = 0u; hwB[i] = 0u; }

    const char* gA = (const char*)(ig + (size_t)cA * SEQ * GATES);
    const char* gB = (const char*)(ig + (size_t)cB * SEQ * GATES);

    // prologue: stage steps 0..15 of both chains into buffer 0
#pragma unroll
    for (int i = 0; i < 6; ++i) {
        __builtin_amdgcn_global_load_lds(AS1(gA + i * 1024 + p * 16),
                                         AS3((char*)&iglA[0][0] + i * 1024), 16, 0, 0);
        __builtin_amdgcn_global_load_lds(AS1(gB + i * 1024 + p * 16),
                                         AS3((char*)&iglB[0][0] + i * 1024), 16, 0, 0);
    }
    asm volatile("s_waitcnt vmcnt(0)" ::: "memory");

    for (int sb = 0; sb < SEQ; sb += 16) {
        const int buf = (sb >> 4) & 1;
        {   // prefetch steps sb+16..sb+31 of both chains into the other buffer
            const int nb = (sb + 16 < SEQ) ? sb + 16 : sb;
            const char* srcA = gA + (size_t)nb * (GATES * 2);
            const char* srcB = gB + (size_t)nb * (GATES * 2);
            char* dstA = (char*)&iglA[buf ^ 1][0];
            char* dstB = (char*)&iglB[buf ^ 1][0];
#pragma unroll
            for (int i = 0; i < 6; ++i) {
                __builtin_amdgcn_global_load_lds(AS1(srcA + i * 1024 + p * 16),
                                                 AS3(dstA + i * 1024), 16, 0, 0);
                __builtin_amdgcn_global_load_lds(AS1(srcB + i * 1024 + p * 16),
                                                 AS3(dstB + i * 1024), 16, 0, 0);
            }
        }

#pragma unroll 4
        for (int u = 0; u < 16; ++u) {
            const int s = sb + u;
            const unsigned short* ia = (const unsigned short*)&iglA[buf][0] + u * GATES;
            const unsigned short* ib = (const unsigned short*)&iglB[buf][0] + u * GATES;
            // ig reads for this step (consumed after the 192-cy dot block)
            const unsigned short urA = ia[p], uzA = ia[PROJ + p], unA = ia[2 * PROJ + p];
            const unsigned short urB = ib[p], uzB = ib[PROJ + p], unB = ib[2 * PROJ + p];

            // ================= chain A =================
            {
                float ar[4] = {0.f,0.f,0.f,0.f}, az[4] = {0.f,0.f,0.f,0.f}, an[4] = {0.f,0.f,0.f,0.f};
#pragma unroll
                for (int i = 0; i < 32; ++i) {
                    const unsigned int h2 = hwA[i];
                    ar[i & 3] = fdot2u(h2, wru[i], ar[i & 3]);
                    an[i & 3] = fdot2u(h2, wnu[i], an[i & 3]);
                    az[i & 3] = fdot2u(h2, wzu[i], az[i & 3]);
                }
                const float hgr = (ar[0] + ar[1]) + (ar[2] + ar[3]);
                const float hgn = (an[0] + an[1]) + (an[2] + an[3]);
                const float hgz = (az[0] + az[1]) + (az[2] + az[3]);

                const float r = __builtin_amdgcn_rcpf(1.f + __expf(-(bf2f(urA) + hgr)));
                const float z = __builtin_amdgcn_rcpf(1.f + __expf(-(bf2f(uzA) + hgz)));
                const float y  = bf2f(unA) + r * (hgn + bn);
                const float e2 = __expf(2.f * y);
                const float nn = 1.f - 2.f * __builtin_amdgcn_rcpf(1.f + e2);
                const float hnew = nn + z * (hregA - nn);
                hregA = hnew;

                union { _Float16 h; unsigned short u; } cv; cv.h = (_Float16)hnew;
                hA16[p] = cv.u;
#pragma unroll
                for (int q = 0; q < 8; ++q) {
                    const uint4 v = ((const uint4*)hA16)[q];
                    hwA[4*q+0] = v.x; hwA[4*q+1] = v.y; hwA[4*q+2] = v.z; hwA[4*q+3] = v.w;
                }
                __builtin_amdgcn_sched_barrier(0);   // pin A's write+reads here
                ys[((size_t)s * CHAINS + cA) * PROJ + p] = f2bf(hnew);
            }

            // ================= chain B =================
            {
                float ar[4] = {0.f,0.f,0.f,0.f}, az[4] = {0.f,0.f,0.f,0.f}, an[4] = {0.f,0.f,0.f,0.f};
#pragma unroll
                for (int i = 0; i < 32; ++i) {
                    const unsigned int h2 = hwB[i];
                    ar[i & 3] = fdot2u(h2, wru[i], ar[i & 3]);
                    an[i & 3] = fdot2u(h2, wnu[i], an[i & 3]);
                    az[i & 3] = fdot2u(h2, wzu[i], az[i & 3]);
                }
                const float hgr = (ar[0] + ar[1]) + (ar[2] + ar[3]);
                const float hgn = (an[0] + an[1]) + (an[2] + an[3]);
                const float hgz = (az[0] + az[1]) + (az[2] + az[3]);

                const float r = __builtin_amdgcn_rcpf(1.f + __expf(-(bf2f(urB) + hgr)));
                const float z = __builtin_amdgcn_rcpf(1.f + __expf(-(bf2f(uzB) + hgz)));
                const float y  = bf2f(unB) + r * (hgn + bn);
                const float e2 = __expf(2.f * y);
                const float nn = 1.f - 2.f * __builtin_amdgcn_rcpf(1.f + e2);
                const float hnew = nn + z * (hregB - nn);
                hregB = hnew;

                union { _Float16 h; unsigned short u; } cv; cv.h = (_Float16)hnew;
                hB16[p] = cv.u;
#pragma unroll
                for (int q = 0; q < 8; ++q) {
                    const uint4 v = ((const uint4*)hB16)[q];
                    hwB[4*q+0] = v.x; hwB[4*q+1] = v.y; hwB[4*q+2] = v.z; hwB[4*q+3] = v.w;
                }
                __builtin_amdgcn_sched_barrier(0);   // pin B's write+reads here
                ys[((size_t)s * CHAINS + cB) * PROJ + p] = f2bf(hnew);
            }
        }
        // next buffer's 12 loads are the oldest VMEM ops; don't drain ys stores
        asm volatile("s_waitcnt vmcnt(32)" ::: "memory");
    }
}

// ---------------------------------------------------------------------------
extern "C" void kernel_launch(void* const* d_in, const int* in_sizes, int n_in,
                              void* d_out, int out_size, void* d_ws, size_t ws_size,
                              hipStream_t stream) {
    const float* x     = (const float*)d_in[0];  // [S,B,E]
    const float* w_in  = (const float*)d_in[1];  // [E=1024, H*P=512]
    const float* w_ih  = (const float*)d_in[2];  // [192,64]  (BT layout [N][K])
    const float* w_hh  = (const float*)d_in[3];  // [192,64]
    const float* b_ih  = (const float*)d_in[4];  // [192]
    const float* b_n   = (const float*)d_in[5];  // [64]
    const float* w_out = (const float*)d_in[6];  // [H*P=512, E=1024]
    float* out = (float*)d_out;                  // [S,B,E] f32

    char* ws = (char*)d_ws;
    const size_t xp_bytes  = (size_t)SEQ * CHAINS * PROJ * 2;      // 16,777,216
    const size_t ig_bytes  = (size_t)SEQ * CHAINS * GATES * 2;     // 50,331,648
    unsigned short* xp_bf  = (unsigned short*)(ws);
    unsigned short* ysb    = (unsigned short*)(ws);                // reuse
    unsigned short* ig     = (unsigned short*)(ws + xp_bytes);     // [c][s][g]
    unsigned short* w_inT  = (unsigned short*)(ws + xp_bytes + ig_bytes);
    unsigned short* w_outT = w_inT + (size_t)512 * 1024;
    unsigned short* w_ihb  = w_outT + (size_t)1024 * 512;
    unsigned short* w_hh16 = w_ihb + (size_t)GATES * PROJ;

    // 0) weight preprocessing
    transpose_to_bf16<<<dim3(512 / 32, 1024 / 32), 256, 0, stream>>>(w_in, w_inT, 1024, 512);
    transpose_to_bf16<<<dim3(1024 / 32, 512 / 32), 256, 0, stream>>>(w_out, w_outT, 512, 1024);
    convert_bf16<<<(GATES * PROJ + 255) / 256, 256, 0, stream>>>(w_ih, w_ihb, GATES * PROJ);
    convert_f16<<<(GATES * PROJ + 255) / 256, 256, 0, stream>>>(w_hh, w_hh16, GATES * PROJ);

    // 1) xp = x @ w_in      [16384 x 512], K=1024
    gemm_mfma<128, 128, 64, true, unsigned short, false, false>
        <<<dim3(16384 / 128, 512 / 128), 256, 0, stream>>>(
            x, w_inT, xp_bf, nullptr, 16384, 512, 1024);

    // 2) ig = xp @ w_ih^T + b_ih   [131072 x 192], K=64; output PERMUTED to [c][s][g]
    gemm_mfma<128, 64, 64, false, unsigned short, true, true>
        <<<dim3(131072 / 128, 192 / 64), 128, 0, stream>>>(
            xp_bf, w_ihb, ig, b_ih, 131072, 192, 64);

    // 3) GRU scan: 2 chains per wave, 32 blocks (ys bf16 overwrites xp region)
    gru_scan6<<<CHAINS / 2, 64, 0, stream>>>(w_hh16, b_n, ig, ysb);

    // 4) out = ys @ w_out   [16384 x 1024], K=512
    gemm_mfma<128, 128, 64, false, float, false, false>
        <<<dim3(16384 / 128, 1024 / 128), 256, 0, stream>>>(
            ysb, w_outT, out, nullptr, 16384, 1024, 512);
}